// Round 1
// baseline (2147.371 us; speedup 1.0000x reference)
//
#include <hip/hip_runtime.h>
#include <cstdint>
#include <cstddef>

// ---------------------------------------------------------------------------
// Shapes (fixed by the problem):
//   x: (2, 8, 96, 96, 192) fp32 ; windows 1x8x8 ; NH=2 ; hd=96 ; L=512 ; MLP 768
//   tokens N = 2*8*96*96 = 147456 ; Bp = 288 windows-batch ; Dn = 8 temporal blocks
// ---------------------------------------------------------------------------

typedef float   f32x4  __attribute__((ext_vector_type(4)));
typedef __bf16  bf16x8 __attribute__((ext_vector_type(8)));
typedef unsigned int   u32x4  __attribute__((ext_vector_type(4)));
typedef unsigned short u16x4  __attribute__((ext_vector_type(4)));

#define DEVI __device__ __forceinline__

DEVI float bf2f(unsigned short u) {
    union { unsigned int i; float f; } v; v.i = ((unsigned int)u) << 16; return v.f;
}
DEVI unsigned short f2bf(float f) {
    unsigned int u = __builtin_bit_cast(unsigned int, f);
    unsigned int r = u + 0x7fffu + ((u >> 16) & 1u);   // RNE
    return (unsigned short)(r >> 16);
}

// ---------------------------------------------------------------------------
// K1: LayerNorm(norm3) + window partition -> h bf16 [Bp=288][L=512][C=192]
// one wave per token
// ---------------------------------------------------------------------------
__global__ __launch_bounds__(256) void k_ln3(const float* __restrict__ x,
                                             const float* __restrict__ g,
                                             const float* __restrict__ bsh,
                                             unsigned short* __restrict__ h) {
    int w = threadIdx.x >> 6, lane = threadIdx.x & 63;
    int token = blockIdx.x * 4 + w;
    const float* xp = x + (size_t)token * 192;
    float v0 = xp[lane], v1 = xp[lane + 64], v2 = xp[lane + 128];
    float s = v0 + v1 + v2;
#pragma unroll
    for (int off = 32; off; off >>= 1) s += __shfl_xor(s, off);
    float mean = s * (1.f / 192.f);
    float d0 = v0 - mean, d1 = v1 - mean, d2 = v2 - mean;
    float q = d0 * d0 + d1 * d1 + d2 * d2;
#pragma unroll
    for (int off = 32; off; off >>= 1) q += __shfl_xor(q, off);
    float rs = rsqrtf(q * (1.f / 192.f) + 1e-5f);
    // token -> (b,d,hh,ww) -> windowed (bp,l)
    int b  = token / (8 * 96 * 96);
    int r0 = token - b * (8 * 96 * 96);
    int d  = r0 / (96 * 96);
    int r1 = r0 - d * (96 * 96);
    int hh = r1 / 96;
    int ww = r1 - hh * 96;
    int bp = b * 144 + (hh >> 3) * 12 + (ww >> 3);
    int l  = d * 64 + (hh & 7) * 8 + (ww & 7);
    unsigned short* hp = h + ((size_t)bp * 512 + l) * 192;
    hp[lane]       = f2bf(d0 * rs * g[lane]       + bsh[lane]);
    hp[lane + 64]  = f2bf(d1 * rs * g[lane + 64]  + bsh[lane + 64]);
    hp[lane + 128] = f2bf(d2 * rs * g[lane + 128] + bsh[lane + 128]);
}

// ---------------------------------------------------------------------------
// K5: LayerNorm(norm4) in natural layout -> xn4 bf16
// ---------------------------------------------------------------------------
__global__ __launch_bounds__(256) void k_ln4(const float* __restrict__ yv,
                                             const float* __restrict__ g,
                                             const float* __restrict__ bsh,
                                             unsigned short* __restrict__ xn) {
    int w = threadIdx.x >> 6, lane = threadIdx.x & 63;
    size_t token = (size_t)blockIdx.x * 4 + w;
    const float* xp = yv + token * 192;
    float v0 = xp[lane], v1 = xp[lane + 64], v2 = xp[lane + 128];
    float s = v0 + v1 + v2;
#pragma unroll
    for (int off = 32; off; off >>= 1) s += __shfl_xor(s, off);
    float mean = s * (1.f / 192.f);
    float d0 = v0 - mean, d1 = v1 - mean, d2 = v2 - mean;
    float q = d0 * d0 + d1 * d1 + d2 * d2;
#pragma unroll
    for (int off = 32; off; off >>= 1) q += __shfl_xor(q, off);
    float rs = rsqrtf(q * (1.f / 192.f) + 1e-5f);
    unsigned short* op = xn + token * 192;
    op[lane]       = f2bf(d0 * rs * g[lane]       + bsh[lane]);
    op[lane + 64]  = f2bf(d1 * rs * g[lane + 64]  + bsh[lane + 64]);
    op[lane + 128] = f2bf(d2 * rs * g[lane + 128] + bsh[lane + 128]);
}

// ---------------------------------------------------------------------------
// Generic GEMM: out[n,m] = sum_k A[n,k] * Bw[m,k] (+epilogue)
// A: bf16 row-major [Nrows][K]; Bw: fp32 row-major [M][K] (torch Linear weight)
// 64x64 tile, 256 threads (4 waves), MFMA 16x16x32 bf16.
// EPI: 0 = qkv store (scale q cols by 1/sqrt(96), bf16, ld=M)
//      1 = out_proj: window-reverse + x residual -> y fp32 (natural layout)
//      2 = fc1 + exact gelu -> bf16 (ld=M)
//      3 = fc2 + y residual -> fp32 out (ld=192)
// ---------------------------------------------------------------------------
template <int EPI>
__global__ __launch_bounds__(256) void k_gemm(const unsigned short* __restrict__ A,
                                              int K, int M,
                                              const float* __restrict__ Bw,
                                              const float* __restrict__ bias,
                                              unsigned short* __restrict__ outb,
                                              float* __restrict__ outf,
                                              const float* __restrict__ res) {
    __shared__ unsigned short As[64][72];   // +8 pad: row stride 144B -> conflict-light
    __shared__ unsigned short Bs[64][72];
    int tid = threadIdx.x;
    int row0 = blockIdx.y * 64, col0 = blockIdx.x * 64;
    int wv = tid >> 6, lane = tid & 63, lr = lane & 15, lg = lane >> 4;
    f32x4 acc[4] = {};

    for (int k0 = 0; k0 < K; k0 += 64) {
        // stage A (bf16, 16B chunks)
#pragma unroll
        for (int i = 0; i < 2; i++) {
            int c = tid + i * 256;            // 512 chunks of 8 elems
            int r = c >> 3, cc = c & 7;
            u32x4 v = *reinterpret_cast<const u32x4*>(A + (size_t)(row0 + r) * K + k0 + cc * 8);
            *reinterpret_cast<u32x4*>(&As[r][cc * 8]) = v;
        }
        // stage B (fp32 -> bf16)
#pragma unroll
        for (int i = 0; i < 4; i++) {
            int c = tid + i * 256;            // 1024 chunks of 4 elems
            int r = c >> 4, cc = c & 15;
            f32x4 v = *reinterpret_cast<const f32x4*>(Bw + (size_t)(col0 + r) * K + k0 + cc * 4);
            u16x4 o = { f2bf(v[0]), f2bf(v[1]), f2bf(v[2]), f2bf(v[3]) };
            *reinterpret_cast<u16x4*>(&Bs[r][cc * 4]) = o;
        }
        __syncthreads();
#pragma unroll
        for (int kk = 0; kk < 64; kk += 32) {
            bf16x8 af = __builtin_bit_cast(bf16x8,
                *reinterpret_cast<const u32x4*>(&As[wv * 16 + lr][kk + lg * 8]));
#pragma unroll
            for (int ct = 0; ct < 4; ct++) {
                bf16x8 bfr = __builtin_bit_cast(bf16x8,
                    *reinterpret_cast<const u32x4*>(&Bs[ct * 16 + lr][kk + lg * 8]));
                acc[ct] = __builtin_amdgcn_mfma_f32_16x16x32_bf16(af, bfr, acc[ct], 0, 0, 0);
            }
        }
        __syncthreads();
    }

#pragma unroll
    for (int ct = 0; ct < 4; ct++) {
#pragma unroll
        for (int rr = 0; rr < 4; rr++) {
            int n   = row0 + wv * 16 + lg * 4 + rr;    // verified D mapping
            int col = col0 + ct * 16 + lr;
            float val = acc[ct][rr];
            if constexpr (EPI == 0) {
                float t = val + bias[col];
                if (col < 192) t *= 0.1020620726159658f;   // 1/sqrt(96) folded into q
                outb[(size_t)n * M + col] = f2bf(t);
            } else if constexpr (EPI == 1) {
                int bp = n >> 9, l = n & 511;
                int b = bp / 144, p = bp - b * 144;
                int hn = p / 12, wn = p - hn * 12;
                int dn = l >> 6, t_ = l & 63;
                size_t tok = ((size_t)((b * 8 + dn) * 96 + hn * 8 + (t_ >> 3)) * 96 + wn * 8 + (t_ & 7));
                size_t idx = tok * 192 + col;
                outf[idx] = res[idx] + val + bias[col];
            } else if constexpr (EPI == 2) {
                float v = val + bias[col];
                float gz = 0.5f * v * (1.f + erff(v * 0.70710678118654752f));
                outb[(size_t)n * M + col] = f2bf(gz);
            } else {
                size_t idx = (size_t)n * 192 + col;
                outf[idx] = res[idx] + val + bias[col];
            }
        }
    }
}

// ---------------------------------------------------------------------------
// K3: block-causal attention, vector math (round-0 correctness-first).
// One block per (bp, head, dn_q): Q tile 64x96, iterate dn_k <= dn_q with
// online softmax. O kept in registers (thread owns 4 rows x 6 dims).
// qkv layout: [bp*512+l][576] bf16, q cols 0..191 (pre-scaled), k 192..383, v 384..575
// out: attn bf16 [bp*512+l][192], c = head*96+d
// ---------------------------------------------------------------------------
__global__ __launch_bounds__(256) void k_attn(const unsigned short* __restrict__ qkv,
                                              unsigned short* __restrict__ aout) {
    __shared__ float Qs[64][97], Ks[64][97], Vs[64][97], Sb[64][65];
    __shared__ float mrow[64], lrow[64], corr[64];
    int blk = blockIdx.x;
    int bp = blk >> 4, rest = blk & 15, head = rest >> 3, dnq = rest & 7;
    int tid = threadIdx.x;
    int tr = tid >> 4, tc = tid & 15;     // 16x16 thread grid
    int lrr = tid >> 2, lq = tid & 3;     // loader mapping: 4 threads per row

    size_t rowbase = (size_t)bp * 512 + (size_t)dnq * 64;
    {
        const unsigned short* qp = qkv + (rowbase + lrr) * 576 + head * 96;
#pragma unroll
        for (int j = 0; j < 6; j++) {
            int off = lq * 24 + j * 4;
            u16x4 v = *reinterpret_cast<const u16x4*>(qp + off);
            Qs[lrr][off] = bf2f(v[0]); Qs[lrr][off + 1] = bf2f(v[1]);
            Qs[lrr][off + 2] = bf2f(v[2]); Qs[lrr][off + 3] = bf2f(v[3]);
        }
    }
    if (tid < 64) { mrow[tid] = -1e30f; lrow[tid] = 0.f; }
    float o[4][6] = {};
    __syncthreads();

    for (int dnk = 0; dnk <= dnq; ++dnk) {
        const unsigned short* kp = qkv + ((size_t)bp * 512 + (size_t)dnk * 64 + lrr) * 576 + 192 + head * 96;
        const unsigned short* vp = kp + 192;
#pragma unroll
        for (int j = 0; j < 6; j++) {
            int off = lq * 24 + j * 4;
            u16x4 kv = *reinterpret_cast<const u16x4*>(kp + off);
            u16x4 vv = *reinterpret_cast<const u16x4*>(vp + off);
            Ks[lrr][off] = bf2f(kv[0]); Ks[lrr][off + 1] = bf2f(kv[1]);
            Ks[lrr][off + 2] = bf2f(kv[2]); Ks[lrr][off + 3] = bf2f(kv[3]);
            Vs[lrr][off] = bf2f(vv[0]); Vs[lrr][off + 1] = bf2f(vv[1]);
            Vs[lrr][off + 2] = bf2f(vv[2]); Vs[lrr][off + 3] = bf2f(vv[3]);
        }
        __syncthreads();
        // S = Q K^T  (q already scaled)
        float s[4][4] = {};
#pragma unroll 4
        for (int k = 0; k < 96; k++) {
            float q0 = Qs[tr * 4 + 0][k], q1 = Qs[tr * 4 + 1][k],
                  q2 = Qs[tr * 4 + 2][k], q3 = Qs[tr * 4 + 3][k];
            float c0 = Ks[tc * 4 + 0][k], c1 = Ks[tc * 4 + 1][k],
                  c2 = Ks[tc * 4 + 2][k], c3 = Ks[tc * 4 + 3][k];
            s[0][0] += q0 * c0; s[0][1] += q0 * c1; s[0][2] += q0 * c2; s[0][3] += q0 * c3;
            s[1][0] += q1 * c0; s[1][1] += q1 * c1; s[1][2] += q1 * c2; s[1][3] += q1 * c3;
            s[2][0] += q2 * c0; s[2][1] += q2 * c1; s[2][2] += q2 * c2; s[2][3] += q2 * c3;
            s[3][0] += q3 * c0; s[3][1] += q3 * c1; s[3][2] += q3 * c2; s[3][3] += q3 * c3;
        }
#pragma unroll
        for (int i = 0; i < 4; i++)
#pragma unroll
            for (int j = 0; j < 4; j++) Sb[tr * 4 + i][tc * 4 + j] = s[i][j];
        __syncthreads();
        // online softmax per row (no intra-block mask: mask is block-granular)
        if (tid < 64) {
            int r = tid;
            float mx = -1e30f;
            for (int c = 0; c < 64; c++) mx = fmaxf(mx, Sb[r][c]);
            float mold = mrow[r], mnew = fmaxf(mold, mx);
            float cr = __expf(mold - mnew);
            float ss = 0.f;
            for (int c = 0; c < 64; c++) {
                float p = __expf(Sb[r][c] - mnew);
                Sb[r][c] = p; ss += p;
            }
            lrow[r] = lrow[r] * cr + ss;
            mrow[r] = mnew; corr[r] = cr;
        }
        __syncthreads();
#pragma unroll
        for (int i = 0; i < 4; i++) {
            float cri = corr[tr * 4 + i];
#pragma unroll
            for (int j = 0; j < 6; j++) o[i][j] *= cri;
        }
#pragma unroll 4
        for (int c = 0; c < 64; c++) {
            float p0 = Sb[tr * 4 + 0][c], p1 = Sb[tr * 4 + 1][c],
                  p2 = Sb[tr * 4 + 2][c], p3 = Sb[tr * 4 + 3][c];
            float w0 = Vs[c][tc * 6 + 0], w1 = Vs[c][tc * 6 + 1], w2 = Vs[c][tc * 6 + 2],
                  w3 = Vs[c][tc * 6 + 3], w4 = Vs[c][tc * 6 + 4], w5 = Vs[c][tc * 6 + 5];
            o[0][0] += p0 * w0; o[0][1] += p0 * w1; o[0][2] += p0 * w2;
            o[0][3] += p0 * w3; o[0][4] += p0 * w4; o[0][5] += p0 * w5;
            o[1][0] += p1 * w0; o[1][1] += p1 * w1; o[1][2] += p1 * w2;
            o[1][3] += p1 * w3; o[1][4] += p1 * w4; o[1][5] += p1 * w5;
            o[2][0] += p2 * w0; o[2][1] += p2 * w1; o[2][2] += p2 * w2;
            o[2][3] += p2 * w3; o[2][4] += p2 * w4; o[2][5] += p2 * w5;
            o[3][0] += p3 * w0; o[3][1] += p3 * w1; o[3][2] += p3 * w2;
            o[3][3] += p3 * w3; o[3][4] += p3 * w4; o[3][5] += p3 * w5;
        }
        __syncthreads();
    }
#pragma unroll
    for (int i = 0; i < 4; i++) {
        int r = tr * 4 + i;
        float inv = 1.f / lrow[r];
        unsigned short* op = aout + (rowbase + r) * 192 + head * 96 + tc * 6;
#pragma unroll
        for (int j = 0; j < 6; j++) op[j] = f2bf(o[i][j] * inv);
    }
}

// ---------------------------------------------------------------------------
// Launcher. ws arena (peak ~396.4 MB):
//   [0, 113.2M)      y   fp32  (x + attn residual, natural layout)
//   [113.2M, 283.1M) qkv bf16  [147456][576]         } hidden (226.5MB) aliases
//   [283.1M, 339.7M) h   bf16  [147456][192]         } this whole span later
//   [339.7M, 396.4M) attn bf16 [147456][192] ; xn4 aliases it after attn is dead
// ---------------------------------------------------------------------------
extern "C" void kernel_launch(void* const* d_in, const int* in_sizes, int n_in,
                              void* d_out, int out_size, void* d_ws, size_t ws_size,
                              hipStream_t stream) {
    const float* x    = (const float*)d_in[0];
    const float* n3g  = (const float*)d_in[1];
    const float* n3b  = (const float*)d_in[2];
    const float* wqkv = (const float*)d_in[3];
    const float* bqkv = (const float*)d_in[4];
    const float* wout = (const float*)d_in[5];
    const float* bout = (const float*)d_in[6];
    const float* n4g  = (const float*)d_in[7];
    const float* n4b  = (const float*)d_in[8];
    const float* wfc1 = (const float*)d_in[9];
    const float* bfc1 = (const float*)d_in[10];
    const float* wfc2 = (const float*)d_in[11];
    const float* bfc2 = (const float*)d_in[12];
    float* out = (float*)d_out;

    char* ws = (char*)d_ws;
    float*          y      = (float*)(ws + 0);
    unsigned short* qkv    = (unsigned short*)(ws + 113246208);
    unsigned short* h      = (unsigned short*)(ws + 283115520);
    unsigned short* attn   = (unsigned short*)(ws + 339738624);
    unsigned short* xn4    = (unsigned short*)(ws + 339738624);  // alias attn (dead)
    unsigned short* hidden = (unsigned short*)(ws + 113246208);  // alias qkv+h (dead)

    k_ln3<<<36864, 256, 0, stream>>>(x, n3g, n3b, h);
    k_gemm<0><<<dim3(9, 2304), 256, 0, stream>>>(h, 192, 576, wqkv, bqkv, qkv, nullptr, nullptr);
    k_attn<<<4608, 256, 0, stream>>>(qkv, attn);
    k_gemm<1><<<dim3(3, 2304), 256, 0, stream>>>(attn, 192, 192, wout, bout, nullptr, y, x);
    k_ln4<<<36864, 256, 0, stream>>>(y, n4g, n4b, xn4);
    k_gemm<2><<<dim3(12, 2304), 256, 0, stream>>>(xn4, 192, 768, wfc1, bfc1, hidden, nullptr, nullptr);
    k_gemm<3><<<dim3(3, 2304), 256, 0, stream>>>(hidden, 768, 192, wfc2, bfc2, nullptr, out, y);
}

// Round 2
// 901.736 us; speedup vs baseline: 2.3814x; 2.3814x over previous
//
#include <hip/hip_runtime.h>
#include <cstdint>
#include <cstddef>

// ---------------------------------------------------------------------------
// Shapes (fixed by the problem):
//   x: (2, 8, 96, 96, 192) fp32 ; windows 1x8x8 ; NH=2 ; hd=96 ; L=512 ; MLP 768
//   tokens N = 2*8*96*96 = 147456 ; Bp = 288 windows-batch ; Dn = 8 temporal blocks
// ---------------------------------------------------------------------------

typedef float   f32x4  __attribute__((ext_vector_type(4)));
typedef __bf16  bf16x8 __attribute__((ext_vector_type(8)));
typedef unsigned int   u32x4  __attribute__((ext_vector_type(4)));
typedef unsigned short u16x4  __attribute__((ext_vector_type(4)));

#define DEVI __device__ __forceinline__

DEVI float bf2f(unsigned short u) {
    union { unsigned int i; float f; } v; v.i = ((unsigned int)u) << 16; return v.f;
}
DEVI unsigned short f2bf(float f) {
    unsigned int u = __builtin_bit_cast(unsigned int, f);
    unsigned int r = u + 0x7fffu + ((u >> 16) & 1u);   // RNE
    return (unsigned short)(r >> 16);
}
DEVI float redmax16(float v) {
#pragma unroll
    for (int off = 1; off < 16; off <<= 1) v = fmaxf(v, __shfl_xor(v, off));
    return v;
}
DEVI float redsum16(float v) {
#pragma unroll
    for (int off = 1; off < 16; off <<= 1) v += __shfl_xor(v, off);
    return v;
}

// ---------------------------------------------------------------------------
// K1: LayerNorm(norm3) + window partition -> h bf16 [Bp=288][L=512][C=192]
// ---------------------------------------------------------------------------
__global__ __launch_bounds__(256) void k_ln3(const float* __restrict__ x,
                                             const float* __restrict__ g,
                                             const float* __restrict__ bsh,
                                             unsigned short* __restrict__ h) {
    int w = threadIdx.x >> 6, lane = threadIdx.x & 63;
    int token = blockIdx.x * 4 + w;
    const float* xp = x + (size_t)token * 192;
    float v0 = xp[lane], v1 = xp[lane + 64], v2 = xp[lane + 128];
    float s = v0 + v1 + v2;
#pragma unroll
    for (int off = 32; off; off >>= 1) s += __shfl_xor(s, off);
    float mean = s * (1.f / 192.f);
    float d0 = v0 - mean, d1 = v1 - mean, d2 = v2 - mean;
    float q = d0 * d0 + d1 * d1 + d2 * d2;
#pragma unroll
    for (int off = 32; off; off >>= 1) q += __shfl_xor(q, off);
    float rs = rsqrtf(q * (1.f / 192.f) + 1e-5f);
    int b  = token / (8 * 96 * 96);
    int r0 = token - b * (8 * 96 * 96);
    int d  = r0 / (96 * 96);
    int r1 = r0 - d * (96 * 96);
    int hh = r1 / 96;
    int ww = r1 - hh * 96;
    int bp = b * 144 + (hh >> 3) * 12 + (ww >> 3);
    int l  = d * 64 + (hh & 7) * 8 + (ww & 7);
    unsigned short* hp = h + ((size_t)bp * 512 + l) * 192;
    hp[lane]       = f2bf(d0 * rs * g[lane]       + bsh[lane]);
    hp[lane + 64]  = f2bf(d1 * rs * g[lane + 64]  + bsh[lane + 64]);
    hp[lane + 128] = f2bf(d2 * rs * g[lane + 128] + bsh[lane + 128]);
}

// ---------------------------------------------------------------------------
// K5: LayerNorm(norm4) in natural layout -> xn4 bf16
// ---------------------------------------------------------------------------
__global__ __launch_bounds__(256) void k_ln4(const float* __restrict__ yv,
                                             const float* __restrict__ g,
                                             const float* __restrict__ bsh,
                                             unsigned short* __restrict__ xn) {
    int w = threadIdx.x >> 6, lane = threadIdx.x & 63;
    size_t token = (size_t)blockIdx.x * 4 + w;
    const float* xp = yv + token * 192;
    float v0 = xp[lane], v1 = xp[lane + 64], v2 = xp[lane + 128];
    float s = v0 + v1 + v2;
#pragma unroll
    for (int off = 32; off; off >>= 1) s += __shfl_xor(s, off);
    float mean = s * (1.f / 192.f);
    float d0 = v0 - mean, d1 = v1 - mean, d2 = v2 - mean;
    float q = d0 * d0 + d1 * d1 + d2 * d2;
#pragma unroll
    for (int off = 32; off; off >>= 1) q += __shfl_xor(q, off);
    float rs = rsqrtf(q * (1.f / 192.f) + 1e-5f);
    unsigned short* op = xn + token * 192;
    op[lane]       = f2bf(d0 * rs * g[lane]       + bsh[lane]);
    op[lane + 64]  = f2bf(d1 * rs * g[lane + 64]  + bsh[lane + 64]);
    op[lane + 128] = f2bf(d2 * rs * g[lane + 128] + bsh[lane + 128]);
}

// ---------------------------------------------------------------------------
// Generic GEMM (unchanged from round 0): out[n,m] = sum_k A[n,k]*Bw[m,k]
// ---------------------------------------------------------------------------
template <int EPI>
__global__ __launch_bounds__(256) void k_gemm(const unsigned short* __restrict__ A,
                                              int K, int M,
                                              const float* __restrict__ Bw,
                                              const float* __restrict__ bias,
                                              unsigned short* __restrict__ outb,
                                              float* __restrict__ outf,
                                              const float* __restrict__ res) {
    __shared__ unsigned short As[64][72];
    __shared__ unsigned short Bs[64][72];
    int tid = threadIdx.x;
    int row0 = blockIdx.y * 64, col0 = blockIdx.x * 64;
    int wv = tid >> 6, lane = tid & 63, lr = lane & 15, lg = lane >> 4;
    f32x4 acc[4] = {};

    for (int k0 = 0; k0 < K; k0 += 64) {
#pragma unroll
        for (int i = 0; i < 2; i++) {
            int c = tid + i * 256;
            int r = c >> 3, cc = c & 7;
            u32x4 v = *reinterpret_cast<const u32x4*>(A + (size_t)(row0 + r) * K + k0 + cc * 8);
            *reinterpret_cast<u32x4*>(&As[r][cc * 8]) = v;
        }
#pragma unroll
        for (int i = 0; i < 4; i++) {
            int c = tid + i * 256;
            int r = c >> 4, cc = c & 15;
            f32x4 v = *reinterpret_cast<const f32x4*>(Bw + (size_t)(col0 + r) * K + k0 + cc * 4);
            u16x4 o = { f2bf(v[0]), f2bf(v[1]), f2bf(v[2]), f2bf(v[3]) };
            *reinterpret_cast<u16x4*>(&Bs[r][cc * 4]) = o;
        }
        __syncthreads();
#pragma unroll
        for (int kk = 0; kk < 64; kk += 32) {
            bf16x8 af = __builtin_bit_cast(bf16x8,
                *reinterpret_cast<const u32x4*>(&As[wv * 16 + lr][kk + lg * 8]));
#pragma unroll
            for (int ct = 0; ct < 4; ct++) {
                bf16x8 bfr = __builtin_bit_cast(bf16x8,
                    *reinterpret_cast<const u32x4*>(&Bs[ct * 16 + lr][kk + lg * 8]));
                acc[ct] = __builtin_amdgcn_mfma_f32_16x16x32_bf16(af, bfr, acc[ct], 0, 0, 0);
            }
        }
        __syncthreads();
    }

#pragma unroll
    for (int ct = 0; ct < 4; ct++) {
#pragma unroll
        for (int rr = 0; rr < 4; rr++) {
            int n   = row0 + wv * 16 + lg * 4 + rr;
            int col = col0 + ct * 16 + lr;
            float val = acc[ct][rr];
            if constexpr (EPI == 0) {
                float t = val + bias[col];
                if (col < 192) t *= 0.1020620726159658f;   // 1/sqrt(96) folded into q
                outb[(size_t)n * M + col] = f2bf(t);
            } else if constexpr (EPI == 1) {
                int bp = n >> 9, l = n & 511;
                int b = bp / 144, p = bp - b * 144;
                int hn = p / 12, wn = p - hn * 12;
                int dn = l >> 6, t_ = l & 63;
                size_t tok = ((size_t)((b * 8 + dn) * 96 + hn * 8 + (t_ >> 3)) * 96 + wn * 8 + (t_ & 7));
                size_t idx = tok * 192 + col;
                outf[idx] = res[idx] + val + bias[col];
            } else if constexpr (EPI == 2) {
                float v = val + bias[col];
                float gz = 0.5f * v * (1.f + erff(v * 0.70710678118654752f));
                outb[(size_t)n * M + col] = f2bf(gz);
            } else {
                size_t idx = (size_t)n * 192 + col;
                outf[idx] = res[idx] + val + bias[col];
            }
        }
    }
}

// ---------------------------------------------------------------------------
// K3: block-causal attention, MFMA version.
// One WG (4 waves) per (bp, head, dnq). Wave w owns Q rows [w*16, w*16+16).
// Per dnk <= dnq: stage K [64][104] row-major and V transposed [96][88] in LDS,
// S = QK^T via 16x16x32 MFMA (A=Q frags in regs, B=K rows), online softmax in
// registers (row-reduce = shfl_xor over the 16-lane group), P -> per-wave LDS
// tile (D-layout write, A-layout b128 read), PV via MFMA with Vt B-frags.
// All LDS row strides are multiples of 16B with only free 2-way bank aliasing.
// qkv: [bp*512+l][576] bf16, q cols 0..191 (pre-scaled by 1/sqrt(96)),
// k 192..383, v 384..575.  out: attn bf16 [bp*512+l][192].
// ---------------------------------------------------------------------------
__global__ __launch_bounds__(256) void k_attn(const unsigned short* __restrict__ qkv,
                                              unsigned short* __restrict__ aout) {
    __shared__ unsigned short Ks[64][104];   // 208B stride: 16B-mult, 2-way only
    __shared__ unsigned short Vt[96][88];    // 176B stride: 16B-mult, 2-way only
    __shared__ unsigned short Ps[4][16][88]; // per-wave P tile

    int blk = blockIdx.x;
    int bp = blk >> 4, rest = blk & 15, head = rest >> 3, dnq = rest & 7;
    int tid = threadIdx.x, wv = tid >> 6, lane = tid & 63;
    int lr = lane & 15, lg = lane >> 4;

    size_t qrow0 = (size_t)bp * 512 + (size_t)dnq * 64;

    // Q A-fragments in registers: lane holds Q[row=lr][k = ks*32 + lg*8 .. +7]
    bf16x8 qf[3];
    {
        const unsigned short* qp = qkv + (qrow0 + wv * 16 + lr) * 576 + head * 96 + lg * 8;
#pragma unroll
        for (int ks = 0; ks < 3; ks++)
            qf[ks] = __builtin_bit_cast(bf16x8, *reinterpret_cast<const u32x4*>(qp + ks * 32));
    }

    f32x4 o[6] = {};                       // O[row=lg*4+rr][d = nf*16+lr]
    float m[4] = {-1e30f, -1e30f, -1e30f, -1e30f};
    float lsum[4] = {0.f, 0.f, 0.f, 0.f};

    for (int dnk = 0; dnk <= dnq; ++dnk) {
        __syncthreads();   // previous iter's reads of Ks/Vt done
        size_t krow0 = (size_t)bp * 512 + (size_t)dnk * 64;
        // stage K: 768 chunks of 8 bf16
#pragma unroll
        for (int i = 0; i < 3; i++) {
            int c = tid + i * 256;
            int r = c / 12, cc = c - r * 12;
            u32x4 v = *reinterpret_cast<const u32x4*>(
                qkv + (krow0 + r) * 576 + 192 + head * 96 + cc * 8);
            *reinterpret_cast<u32x4*>(&Ks[r][cc * 8]) = v;
        }
        // stage V transposed: 1536 quads
#pragma unroll
        for (int i = 0; i < 6; i++) {
            int t = tid + i * 256;
            int tok = t / 24, d0 = (t - tok * 24) * 4;
            u16x4 v = *reinterpret_cast<const u16x4*>(
                qkv + (krow0 + tok) * 576 + 384 + head * 96 + d0);
            Vt[d0][tok] = v[0]; Vt[d0 + 1][tok] = v[1];
            Vt[d0 + 2][tok] = v[2]; Vt[d0 + 3][tok] = v[3];
        }
        __syncthreads();

        // S = Q K^T : lane holds S[row=lg*4+rr][kcol = ct*16+lr]
        f32x4 s[4] = {};
#pragma unroll
        for (int ks = 0; ks < 3; ks++) {
#pragma unroll
            for (int ct = 0; ct < 4; ct++) {
                bf16x8 kf = __builtin_bit_cast(bf16x8,
                    *reinterpret_cast<const u32x4*>(&Ks[ct * 16 + lr][ks * 32 + lg * 8]));
                s[ct] = __builtin_amdgcn_mfma_f32_16x16x32_bf16(qf[ks], kf, s[ct], 0, 0, 0);
            }
        }

        // online softmax (block-granular mask => no masking inside tile)
        float p[4][4];
        float corr[4];
#pragma unroll
        for (int rr = 0; rr < 4; rr++) {
            float mx = fmaxf(fmaxf(s[0][rr], s[1][rr]), fmaxf(s[2][rr], s[3][rr]));
            mx = redmax16(mx);
            float mnew = fmaxf(m[rr], mx);
            corr[rr] = __expf(m[rr] - mnew);
            m[rr] = mnew;
            float ps = 0.f;
#pragma unroll
            for (int ct = 0; ct < 4; ct++) {
                float pv = __expf(s[ct][rr] - mnew);
                p[ct][rr] = pv; ps += pv;
            }
            ps = redsum16(ps);
            lsum[rr] = lsum[rr] * corr[rr] + ps;
        }
#pragma unroll
        for (int nf = 0; nf < 6; nf++)
#pragma unroll
            for (int rr = 0; rr < 4; rr++) o[nf][rr] *= corr[rr];

        // P -> LDS (D-layout write), read back as A-fragments
#pragma unroll
        for (int ct = 0; ct < 4; ct++)
#pragma unroll
            for (int rr = 0; rr < 4; rr++)
                Ps[wv][lg * 4 + rr][ct * 16 + lr] = f2bf(p[ct][rr]);
        __syncthreads();

        // PV: o += P @ V   (B-frags from Vt)
#pragma unroll
        for (int kk = 0; kk < 2; kk++) {
            bf16x8 pf = __builtin_bit_cast(bf16x8,
                *reinterpret_cast<const u32x4*>(&Ps[wv][lr][kk * 32 + lg * 8]));
#pragma unroll
            for (int nf = 0; nf < 6; nf++) {
                bf16x8 vf = __builtin_bit_cast(bf16x8,
                    *reinterpret_cast<const u32x4*>(&Vt[nf * 16 + lr][kk * 32 + lg * 8]));
                o[nf] = __builtin_amdgcn_mfma_f32_16x16x32_bf16(pf, vf, o[nf], 0, 0, 0);
            }
        }
    }

    // epilogue: divide by l, store bf16
    float inv[4];
#pragma unroll
    for (int rr = 0; rr < 4; rr++) inv[rr] = 1.f / lsum[rr];
#pragma unroll
    for (int nf = 0; nf < 6; nf++) {
#pragma unroll
        for (int rr = 0; rr < 4; rr++) {
            size_t row = qrow0 + wv * 16 + lg * 4 + rr;
            aout[row * 192 + head * 96 + nf * 16 + lr] = f2bf(o[nf][rr] * inv[rr]);
        }
    }
}

// ---------------------------------------------------------------------------
// Launcher. ws arena (peak ~396.4 MB):
//   [0, 113.2M)      y   fp32  (x + attn residual, natural layout)
//   [113.2M, 283.1M) qkv bf16  [147456][576]         } hidden (226.5MB) aliases
//   [283.1M, 339.7M) h   bf16  [147456][192]         } this whole span later
//   [339.7M, 396.4M) attn bf16 [147456][192] ; xn4 aliases it after attn is dead
// ---------------------------------------------------------------------------
extern "C" void kernel_launch(void* const* d_in, const int* in_sizes, int n_in,
                              void* d_out, int out_size, void* d_ws, size_t ws_size,
                              hipStream_t stream) {
    const float* x    = (const float*)d_in[0];
    const float* n3g  = (const float*)d_in[1];
    const float* n3b  = (const float*)d_in[2];
    const float* wqkv = (const float*)d_in[3];
    const float* bqkv = (const float*)d_in[4];
    const float* wout = (const float*)d_in[5];
    const float* bout = (const float*)d_in[6];
    const float* n4g  = (const float*)d_in[7];
    const float* n4b  = (const float*)d_in[8];
    const float* wfc1 = (const float*)d_in[9];
    const float* bfc1 = (const float*)d_in[10];
    const float* wfc2 = (const float*)d_in[11];
    const float* bfc2 = (const float*)d_in[12];
    float* out = (float*)d_out;

    char* ws = (char*)d_ws;
    float*          y      = (float*)(ws + 0);
    unsigned short* qkv    = (unsigned short*)(ws + 113246208);
    unsigned short* h      = (unsigned short*)(ws + 283115520);
    unsigned short* attn   = (unsigned short*)(ws + 339738624);
    unsigned short* xn4    = (unsigned short*)(ws + 339738624);  // alias attn (dead)
    unsigned short* hidden = (unsigned short*)(ws + 113246208);  // alias qkv+h (dead)

    k_ln3<<<36864, 256, 0, stream>>>(x, n3g, n3b, h);
    k_gemm<0><<<dim3(9, 2304), 256, 0, stream>>>(h, 192, 576, wqkv, bqkv, qkv, nullptr, nullptr);
    k_attn<<<4608, 256, 0, stream>>>(qkv, attn);
    k_gemm<1><<<dim3(3, 2304), 256, 0, stream>>>(attn, 192, 192, wout, bout, nullptr, y, x);
    k_ln4<<<36864, 256, 0, stream>>>(y, n4g, n4b, xn4);
    k_gemm<2><<<dim3(12, 2304), 256, 0, stream>>>(xn4, 192, 768, wfc1, bfc1, hidden, nullptr, nullptr);
    k_gemm<3><<<dim3(3, 2304), 256, 0, stream>>>(hidden, 768, 192, wfc2, bfc2, nullptr, out, y);
}

// Round 3
// 718.520 us; speedup vs baseline: 2.9886x; 1.2550x over previous
//
#include <hip/hip_runtime.h>
#include <cstdint>
#include <cstddef>

// ---------------------------------------------------------------------------
// Shapes: x (2,8,96,96,192) fp32 ; windows 1x8x8 ; NH=2 ; hd=96 ; L=512 ; MLP 768
// tokens N = 147456 ; Bp = 288 ; Dn = 8
// ---------------------------------------------------------------------------

typedef float   f32x4  __attribute__((ext_vector_type(4)));
typedef __bf16  bf16x8 __attribute__((ext_vector_type(8)));
typedef unsigned int   u32x4  __attribute__((ext_vector_type(4)));
typedef unsigned short u16x4  __attribute__((ext_vector_type(4)));

#define DEVI __device__ __forceinline__

DEVI float bf2f(unsigned short u) {
    union { unsigned int i; float f; } v; v.i = ((unsigned int)u) << 16; return v.f;
}
DEVI unsigned short f2bf(float f) {
    unsigned int u = __builtin_bit_cast(unsigned int, f);
    unsigned int r = u + 0x7fffu + ((u >> 16) & 1u);   // RNE
    return (unsigned short)(r >> 16);
}

// ---------------------------------------------------------------------------
// K0: convert + pad weights fp32 -> bf16.
// wqkv [576][192]->[640][192]; wout [192][192]->[256][192];
// wfc1 [768][192]->[768][192]; wfc2 [192][768]->[256][768]. Pad rows = 0.
// ---------------------------------------------------------------------------
__global__ __launch_bounds__(256) void k_wconv(const float* __restrict__ wqkv,
                                               const float* __restrict__ wout,
                                               const float* __restrict__ wfc1,
                                               const float* __restrict__ wfc2,
                                               unsigned short* __restrict__ oq,
                                               unsigned short* __restrict__ oo,
                                               unsigned short* __restrict__ o1,
                                               unsigned short* __restrict__ o2) {
    int i = blockIdx.x * 256 + threadIdx.x;
    if (i < 122880) {                       // [640][192]
        int r = i / 192;
        oq[i] = (r < 576) ? f2bf(wqkv[i]) : (unsigned short)0;
    } else if (i < 172032) {                // [256][192]
        int j = i - 122880; int r = j / 192;
        oo[j] = (r < 192) ? f2bf(wout[j]) : (unsigned short)0;
    } else if (i < 319488) {                // [768][192]
        int j = i - 172032;
        o1[j] = f2bf(wfc1[j]);
    } else if (i < 516096) {                // [256][768]
        int j = i - 319488; int r = j / 768;
        o2[j] = (r < 192) ? f2bf(wfc2[j]) : (unsigned short)0;
    }
}

// ---------------------------------------------------------------------------
// K1: LayerNorm(norm3) + window partition -> h bf16 [288][512][192]
// ---------------------------------------------------------------------------
__global__ __launch_bounds__(256) void k_ln3(const float* __restrict__ x,
                                             const float* __restrict__ g,
                                             const float* __restrict__ bsh,
                                             unsigned short* __restrict__ h) {
    int w = threadIdx.x >> 6, lane = threadIdx.x & 63;
    int token = blockIdx.x * 4 + w;
    const float* xp = x + (size_t)token * 192;
    float v0 = xp[lane], v1 = xp[lane + 64], v2 = xp[lane + 128];
    float s = v0 + v1 + v2;
#pragma unroll
    for (int off = 32; off; off >>= 1) s += __shfl_xor(s, off);
    float mean = s * (1.f / 192.f);
    float d0 = v0 - mean, d1 = v1 - mean, d2 = v2 - mean;
    float q = d0 * d0 + d1 * d1 + d2 * d2;
#pragma unroll
    for (int off = 32; off; off >>= 1) q += __shfl_xor(q, off);
    float rs = rsqrtf(q * (1.f / 192.f) + 1e-5f);
    int b  = token / (8 * 96 * 96);
    int r0 = token - b * (8 * 96 * 96);
    int d  = r0 / (96 * 96);
    int r1 = r0 - d * (96 * 96);
    int hh = r1 / 96;
    int ww = r1 - hh * 96;
    int bp = b * 144 + (hh >> 3) * 12 + (ww >> 3);
    int l  = d * 64 + (hh & 7) * 8 + (ww & 7);
    unsigned short* hp = h + ((size_t)bp * 512 + l) * 192;
    hp[lane]       = f2bf(d0 * rs * g[lane]       + bsh[lane]);
    hp[lane + 64]  = f2bf(d1 * rs * g[lane + 64]  + bsh[lane + 64]);
    hp[lane + 128] = f2bf(d2 * rs * g[lane + 128] + bsh[lane + 128]);
}

// ---------------------------------------------------------------------------
// K5: LayerNorm(norm4), natural layout -> xn4 bf16
// ---------------------------------------------------------------------------
__global__ __launch_bounds__(256) void k_ln4(const float* __restrict__ yv,
                                             const float* __restrict__ g,
                                             const float* __restrict__ bsh,
                                             unsigned short* __restrict__ xn) {
    int w = threadIdx.x >> 6, lane = threadIdx.x & 63;
    size_t token = (size_t)blockIdx.x * 4 + w;
    const float* xp = yv + token * 192;
    float v0 = xp[lane], v1 = xp[lane + 64], v2 = xp[lane + 128];
    float s = v0 + v1 + v2;
#pragma unroll
    for (int off = 32; off; off >>= 1) s += __shfl_xor(s, off);
    float mean = s * (1.f / 192.f);
    float d0 = v0 - mean, d1 = v1 - mean, d2 = v2 - mean;
    float q = d0 * d0 + d1 * d1 + d2 * d2;
#pragma unroll
    for (int off = 32; off; off >>= 1) q += __shfl_xor(q, off);
    float rs = rsqrtf(q * (1.f / 192.f) + 1e-5f);
    unsigned short* op = xn + token * 192;
    op[lane]       = f2bf(d0 * rs * g[lane]       + bsh[lane]);
    op[lane + 64]  = f2bf(d1 * rs * g[lane + 64]  + bsh[lane + 64]);
    op[lane + 128] = f2bf(d2 * rs * g[lane + 128] + bsh[lane + 128]);
}

// ---------------------------------------------------------------------------
// K2: 128x128-tile GEMM: out[n,m] = sum_k A[n,k] * Bw[m,k] (+epilogue)
// A bf16 [rows][K]; Bw bf16 padded [Npad][K]. 256 thr = 4 waves, each a 64x64
// quadrant (4x4 frags of 16x16x32 MFMA). LDS [128][72] (stride 144B: bank-
// quad (r+cc)%8 uniform => conflict-free b128 r/w).
// EPI 0: qkv -> qk (q scaled) + vt (v transposed, packed 8B)
// EPI 1: out_proj -> window-reverse + x residual -> y fp32 (=d_out)
// EPI 2: fc1 + exact gelu -> hidden bf16
// EPI 3: fc2 + y residual -> out fp32 (in-place on d_out)
// ---------------------------------------------------------------------------
template <int EPI>
__global__ __launch_bounds__(256) void k_gemm128(const unsigned short* __restrict__ A,
                                                 int K,
                                                 const unsigned short* __restrict__ Bw,
                                                 const float* __restrict__ bias,
                                                 unsigned short* __restrict__ outb,
                                                 unsigned short* __restrict__ vt,
                                                 float* __restrict__ outf,
                                                 const float* __restrict__ res) {
    __shared__ unsigned short As[128][72];
    __shared__ unsigned short Bs[128][72];
    const int tid = threadIdx.x;
    const int row0 = blockIdx.y * 128, col0 = blockIdx.x * 128;
    const int wv = tid >> 6, lane = tid & 63, lr = lane & 15, lg = lane >> 4;
    const int wr = wv >> 1, wc = wv & 1;
    f32x4 acc[4][4] = {};

    for (int k0 = 0; k0 < K; k0 += 64) {
#pragma unroll
        for (int i = 0; i < 4; i++) {
            int c = tid + i * 256;
            int r = c >> 3, cc = c & 7;
            u32x4 v = *reinterpret_cast<const u32x4*>(A + (size_t)(row0 + r) * K + k0 + cc * 8);
            *reinterpret_cast<u32x4*>(&As[r][cc * 8]) = v;
        }
#pragma unroll
        for (int i = 0; i < 4; i++) {
            int c = tid + i * 256;
            int r = c >> 3, cc = c & 7;
            u32x4 v = *reinterpret_cast<const u32x4*>(Bw + (size_t)(col0 + r) * K + k0 + cc * 8);
            *reinterpret_cast<u32x4*>(&Bs[r][cc * 8]) = v;
        }
        __syncthreads();
#pragma unroll
        for (int kk = 0; kk < 64; kk += 32) {
            bf16x8 af[4], bf[4];
#pragma unroll
            for (int m = 0; m < 4; m++)
                af[m] = __builtin_bit_cast(bf16x8,
                    *reinterpret_cast<const u32x4*>(&As[wr * 64 + m * 16 + lr][kk + lg * 8]));
#pragma unroll
            for (int n = 0; n < 4; n++)
                bf[n] = __builtin_bit_cast(bf16x8,
                    *reinterpret_cast<const u32x4*>(&Bs[wc * 64 + n * 16 + lr][kk + lg * 8]));
#pragma unroll
            for (int m = 0; m < 4; m++)
#pragma unroll
                for (int n = 0; n < 4; n++)
                    acc[m][n] = __builtin_amdgcn_mfma_f32_16x16x32_bf16(af[m], bf[n], acc[m][n], 0, 0, 0);
        }
        __syncthreads();
    }

#pragma unroll
    for (int m = 0; m < 4; m++) {
#pragma unroll
        for (int n = 0; n < 4; n++) {
            int col  = col0 + wc * 64 + n * 16 + lr;
            int rowb = row0 + wr * 64 + m * 16 + lg * 4;
            if constexpr (EPI == 0) {
                if (col < 384) {
                    float b = bias[col];
                    float sc = (col < 192) ? 0.1020620726159658f : 1.f;  // 1/sqrt(96) on q
#pragma unroll
                    for (int rr = 0; rr < 4; rr++)
                        outb[(size_t)(rowb + rr) * 384 + col] = f2bf((acc[m][n][rr] + b) * sc);
                } else if (col < 576) {
                    float b = bias[col];
                    int head = (col >= 480) ? 1 : 0;
                    int d = col - 384 - head * 96;
                    int bp = rowb >> 9, tok = rowb & 511;
                    u16x4 pk = { f2bf(acc[m][n][0] + b), f2bf(acc[m][n][1] + b),
                                 f2bf(acc[m][n][2] + b), f2bf(acc[m][n][3] + b) };
                    *reinterpret_cast<u16x4*>(vt + ((size_t)(bp * 2 + head) * 96 + d) * 512 + tok) = pk;
                }
            } else if constexpr (EPI == 1) {
                if (col < 192) {
                    float b = bias[col];
#pragma unroll
                    for (int rr = 0; rr < 4; rr++) {
                        int nrow = rowb + rr;
                        int bp = nrow >> 9, l = nrow & 511;
                        int bb = bp / 144, p = bp - bb * 144;
                        int hn = p / 12, wn = p - hn * 12;
                        int dn = l >> 6, t_ = l & 63;
                        size_t tok = ((size_t)((bb * 8 + dn) * 96 + hn * 8 + (t_ >> 3)) * 96 + wn * 8 + (t_ & 7));
                        size_t idx = tok * 192 + col;
                        outf[idx] = res[idx] + acc[m][n][rr] + b;
                    }
                }
            } else if constexpr (EPI == 2) {
                float b = bias[col];
#pragma unroll
                for (int rr = 0; rr < 4; rr++) {
                    float v = acc[m][n][rr] + b;
                    float gz = 0.5f * v * (1.f + erff(v * 0.70710678118654752f));
                    outb[(size_t)(rowb + rr) * 768 + col] = f2bf(gz);
                }
            } else {
                if (col < 192) {
                    float b = bias[col];
#pragma unroll
                    for (int rr = 0; rr < 4; rr++) {
                        size_t idx = (size_t)(rowb + rr) * 192 + col;
                        outf[idx] = res[idx] + acc[m][n][rr] + b;
                    }
                }
            }
        }
    }
}

// ---------------------------------------------------------------------------
// K3: block-causal attention, swapped-QK^T MFMA version.
// One WG (4 waves) per (bp, head, dnq); wave w owns q-rows [w*16, w*16+16).
// S^T = mfma(K, Q) => lane holds all 16 S-values of q-row lr: softmax stats
// are 16 in-reg ops + 2 shfl_xor. P^T packs to vectorized 8B LDS writes.
// V pre-transposed in global (vt) => conflict-free vector staging.
// All LDS bank-quads uniform (Ks stride 104, Vt/Ps stride 72).
// ---------------------------------------------------------------------------
__global__ __launch_bounds__(256) void k_attn(const unsigned short* __restrict__ qk,
                                              const unsigned short* __restrict__ vt,
                                              unsigned short* __restrict__ aout) {
    __shared__ unsigned short Ks[64][104];
    __shared__ unsigned short Vt[96][72];
    __shared__ unsigned short Ps[4][16][72];

    int blk = blockIdx.x;
    int bp = blk >> 4, rest = blk & 15, head = rest >> 3, dnq = rest & 7;
    int tid = threadIdx.x, wv = tid >> 6, lane = tid & 63;
    int lr = lane & 15, lg = lane >> 4;
    size_t qrow0 = (size_t)bp * 512 + (size_t)dnq * 64;

    // Q as B-fragments (col = q-row = lr)
    bf16x8 qf[3];
    {
        const unsigned short* qp = qk + (qrow0 + wv * 16 + lr) * 384 + head * 96 + lg * 8;
#pragma unroll
        for (int ks = 0; ks < 3; ks++)
            qf[ks] = __builtin_bit_cast(bf16x8, *reinterpret_cast<const u32x4*>(qp + ks * 32));
    }

    f32x4 o[6] = {};                 // O[qrow=lg*4+rr][d=nf*16+lr]
    float m_ = -1e30f, lsum = 0.f;   // stats for q-row = lr (dup across lg)
    const unsigned short* vbase = vt + (size_t)(bp * 2 + head) * 96 * 512;

    for (int dnk = 0; dnk <= dnq; ++dnk) {
        __syncthreads();             // prior PV reads of Ks/Vt done
        size_t krow0 = (size_t)bp * 512 + (size_t)dnk * 64;
        // stage K row-major [64][96]: 768 x 16B
#pragma unroll
        for (int i = 0; i < 3; i++) {
            int c = tid + i * 256;
            int r = c / 12, cc = c - r * 12;
            u32x4 v = *reinterpret_cast<const u32x4*>(
                qk + (krow0 + r) * 384 + 192 + head * 96 + cc * 8);
            *reinterpret_cast<u32x4*>(&Ks[r][cc * 8]) = v;
        }
        // stage Vt [96][64]: 768 x 16B (pre-transposed in global)
#pragma unroll
        for (int i = 0; i < 3; i++) {
            int c = tid + i * 256;
            int d = c >> 3, tb = c & 7;
            u32x4 v = *reinterpret_cast<const u32x4*>(
                vbase + (size_t)d * 512 + dnk * 64 + tb * 8);
            *reinterpret_cast<u32x4*>(&Vt[d][tb * 8]) = v;
        }
        __syncthreads();

        // S^T = K Q^T : lane holds S[qrow=lr][kcol = ct*16 + lg*4 + rr]
        f32x4 st[4] = {};
#pragma unroll
        for (int ks = 0; ks < 3; ks++) {
#pragma unroll
            for (int ct = 0; ct < 4; ct++) {
                bf16x8 kf = __builtin_bit_cast(bf16x8,
                    *reinterpret_cast<const u32x4*>(&Ks[ct * 16 + lr][ks * 32 + lg * 8]));
                st[ct] = __builtin_amdgcn_mfma_f32_16x16x32_bf16(kf, qf[ks], st[ct], 0, 0, 0);
            }
        }

        // online softmax for row lr (lanes {lr,lr+16,lr+32,lr+48} cooperate)
        float mx = st[0][0];
#pragma unroll
        for (int ct = 0; ct < 4; ct++)
#pragma unroll
            for (int rr = 0; rr < 4; rr++) mx = fmaxf(mx, st[ct][rr]);
        mx = fmaxf(mx, __shfl_xor(mx, 16));
        mx = fmaxf(mx, __shfl_xor(mx, 32));
        float mnew = fmaxf(m_, mx);
        float corr = __expf(m_ - mnew);
        m_ = mnew;
        float ps = 0.f;
#pragma unroll
        for (int ct = 0; ct < 4; ct++) {
            u16x4 pk;
#pragma unroll
            for (int rr = 0; rr < 4; rr++) {
                float pv = __expf(st[ct][rr] - mnew);
                ps += pv;
                pk[rr] = f2bf(pv);
            }
            *reinterpret_cast<u16x4*>(&Ps[wv][lr][ct * 16 + lg * 4]) = pk;  // per-wave: no barrier
        }
        ps += __shfl_xor(ps, 16);
        ps += __shfl_xor(ps, 32);
        lsum = lsum * corr + ps;

        // rescale O (corr lives at lanes with lr == row; broadcast)
#pragma unroll
        for (int rr = 0; rr < 4; rr++) {
            float cr = __shfl(corr, (lane & 48) | (lg * 4 + rr));
#pragma unroll
            for (int nf = 0; nf < 6; nf++) o[nf][rr] *= cr;
        }

        // PV: O += P @ V  (A = P^T-written rows, B = Vt rows)
#pragma unroll
        for (int kk = 0; kk < 2; kk++) {
            bf16x8 pf = __builtin_bit_cast(bf16x8,
                *reinterpret_cast<const u32x4*>(&Ps[wv][lr][kk * 32 + lg * 8]));
#pragma unroll
            for (int nf = 0; nf < 6; nf++) {
                bf16x8 vf = __builtin_bit_cast(bf16x8,
                    *reinterpret_cast<const u32x4*>(&Vt[nf * 16 + lr][kk * 32 + lg * 8]));
                o[nf] = __builtin_amdgcn_mfma_f32_16x16x32_bf16(pf, vf, o[nf], 0, 0, 0);
            }
        }
    }

    // epilogue: divide by lsum (broadcast per row), store bf16
#pragma unroll
    for (int rr = 0; rr < 4; rr++) {
        float li = __shfl(lsum, (lane & 48) | (lg * 4 + rr));
        float inv = 1.f / li;
        size_t row = qrow0 + wv * 16 + lg * 4 + rr;
#pragma unroll
        for (int nf = 0; nf < 6; nf++)
            aout[row * 192 + head * 96 + nf * 16 + lr] = f2bf(o[nf][rr] * inv);
    }
}

// ---------------------------------------------------------------------------
// Launcher. y lives in d_out (fully rewritten by out_proj each call => replay
// safe). ws arena (peak ~284.1 MB < 396.4 MB used in round 1):
//   [0, 113.2M)        qk bf16 [147456][384]   } hidden [147456][768]
//   [113.2M, 169.9M)   vt bf16 [576][96][512]  }   aliases [0, 226.5M)
//   [169.9M, 226.5M)   h  bf16 [147456][192]   }   at fc1/fc2 time
//   [226.5M, 283.1M)   attn bf16 ; xn4 aliases it after out_proj
//   [283.1M, 284.2M)   bf16 padded weights (wq 640x192, wo 256x192,
//                      w1 768x192, w2 256x768)
// ---------------------------------------------------------------------------
extern "C" void kernel_launch(void* const* d_in, const int* in_sizes, int n_in,
                              void* d_out, int out_size, void* d_ws, size_t ws_size,
                              hipStream_t stream) {
    const float* x    = (const float*)d_in[0];
    const float* n3g  = (const float*)d_in[1];
    const float* n3b  = (const float*)d_in[2];
    const float* wqkv = (const float*)d_in[3];
    const float* bqkv = (const float*)d_in[4];
    const float* wout = (const float*)d_in[5];
    const float* bout = (const float*)d_in[6];
    const float* n4g  = (const float*)d_in[7];
    const float* n4b  = (const float*)d_in[8];
    const float* wfc1 = (const float*)d_in[9];
    const float* bfc1 = (const float*)d_in[10];
    const float* wfc2 = (const float*)d_in[11];
    const float* bfc2 = (const float*)d_in[12];
    float* out = (float*)d_out;

    char* ws = (char*)d_ws;
    unsigned short* qk     = (unsigned short*)(ws + 0);
    unsigned short* vt     = (unsigned short*)(ws + 113246208);
    unsigned short* h      = (unsigned short*)(ws + 169869312);
    unsigned short* attn   = (unsigned short*)(ws + 226492416);
    unsigned short* xn4    = (unsigned short*)(ws + 226492416);   // alias attn
    unsigned short* hidden = (unsigned short*)(ws + 0);           // alias qk+vt+h
    unsigned short* wq_bf  = (unsigned short*)(ws + 283115520);
    unsigned short* wo_bf  = (unsigned short*)(ws + 283361280);
    unsigned short* w1_bf  = (unsigned short*)(ws + 283459584);
    unsigned short* w2_bf  = (unsigned short*)(ws + 283754496);
    float* y = out;   // y = x + attn-out lives in d_out

    k_wconv<<<2016, 256, 0, stream>>>(wqkv, wout, wfc1, wfc2, wq_bf, wo_bf, w1_bf, w2_bf);
    k_ln3<<<36864, 256, 0, stream>>>(x, n3g, n3b, h);
    k_gemm128<0><<<dim3(5, 1152), 256, 0, stream>>>(h, 192, wq_bf, bqkv, qk, vt, nullptr, nullptr);
    k_attn<<<4608, 256, 0, stream>>>(qk, vt, attn);
    k_gemm128<1><<<dim3(2, 1152), 256, 0, stream>>>(attn, 192, wo_bf, bout, nullptr, nullptr, y, x);
    k_ln4<<<36864, 256, 0, stream>>>(y, n4g, n4b, xn4);
    k_gemm128<2><<<dim3(6, 1152), 256, 0, stream>>>(xn4, 192, w1_bf, bfc1, hidden, nullptr, nullptr, nullptr);
    k_gemm128<3><<<dim3(2, 1152), 256, 0, stream>>>(hidden, 768, w2_bf, bfc2, nullptr, nullptr, out, y);
}

// Round 4
// 605.593 us; speedup vs baseline: 3.5459x; 1.1865x over previous
//
#include <hip/hip_runtime.h>
#include <cstdint>
#include <cstddef>

// ---------------------------------------------------------------------------
// Shapes: x (2,8,96,96,192) fp32 ; windows 1x8x8 ; NH=2 ; hd=96 ; L=512 ; MLP 768
// tokens N = 147456 ; Bp = 288 ; Dn = 8
// ---------------------------------------------------------------------------

typedef float   f32x4  __attribute__((ext_vector_type(4)));
typedef __bf16  bf16x8 __attribute__((ext_vector_type(8)));
typedef unsigned int   u32x4  __attribute__((ext_vector_type(4)));
typedef unsigned short u16x4  __attribute__((ext_vector_type(4)));

#define DEVI __device__ __forceinline__

DEVI float bf2f(unsigned short u) {
    union { unsigned int i; float f; } v; v.i = ((unsigned int)u) << 16; return v.f;
}
DEVI unsigned short f2bf(float f) {
    unsigned int u = __builtin_bit_cast(unsigned int, f);
    unsigned int r = u + 0x7fffu + ((u >> 16) & 1u);   // RNE
    return (unsigned short)(r >> 16);
}

// async global->LDS, 16B per lane; LDS dest is wave-uniform base + lane*16
typedef __attribute__((address_space(3))) unsigned char       lds_u8;
typedef __attribute__((address_space(1))) const unsigned char g_u8;
DEVI void gl_lds16(const void* g, void* l) {
    __builtin_amdgcn_global_load_lds((g_u8*)g, (lds_u8*)l, 16, 0, 0);
}

// ---------------------------------------------------------------------------
// K0: convert + pad weights fp32 -> bf16.
// ---------------------------------------------------------------------------
__global__ __launch_bounds__(256) void k_wconv(const float* __restrict__ wqkv,
                                               const float* __restrict__ wout,
                                               const float* __restrict__ wfc1,
                                               const float* __restrict__ wfc2,
                                               unsigned short* __restrict__ oq,
                                               unsigned short* __restrict__ oo,
                                               unsigned short* __restrict__ o1,
                                               unsigned short* __restrict__ o2) {
    int i = blockIdx.x * 256 + threadIdx.x;
    if (i < 122880) {                       // [640][192]
        int r = i / 192;
        oq[i] = (r < 576) ? f2bf(wqkv[i]) : (unsigned short)0;
    } else if (i < 172032) {                // [256][192]
        int j = i - 122880; int r = j / 192;
        oo[j] = (r < 192) ? f2bf(wout[j]) : (unsigned short)0;
    } else if (i < 319488) {                // [768][192]
        int j = i - 172032;
        o1[j] = f2bf(wfc1[j]);
    } else if (i < 516096) {                // [256][768]
        int j = i - 319488; int r = j / 768;
        o2[j] = (r < 192) ? f2bf(wfc2[j]) : (unsigned short)0;
    }
}

// ---------------------------------------------------------------------------
// K1: LayerNorm(norm3) + window partition -> h bf16 [288][512][192]
// ---------------------------------------------------------------------------
__global__ __launch_bounds__(256) void k_ln3(const float* __restrict__ x,
                                             const float* __restrict__ g,
                                             const float* __restrict__ bsh,
                                             unsigned short* __restrict__ h) {
    int w = threadIdx.x >> 6, lane = threadIdx.x & 63;
    int token = blockIdx.x * 4 + w;
    const float* xp = x + (size_t)token * 192;
    float v0 = xp[lane], v1 = xp[lane + 64], v2 = xp[lane + 128];
    float s = v0 + v1 + v2;
#pragma unroll
    for (int off = 32; off; off >>= 1) s += __shfl_xor(s, off);
    float mean = s * (1.f / 192.f);
    float d0 = v0 - mean, d1 = v1 - mean, d2 = v2 - mean;
    float q = d0 * d0 + d1 * d1 + d2 * d2;
#pragma unroll
    for (int off = 32; off; off >>= 1) q += __shfl_xor(q, off);
    float rs = rsqrtf(q * (1.f / 192.f) + 1e-5f);
    int b  = token / (8 * 96 * 96);
    int r0 = token - b * (8 * 96 * 96);
    int d  = r0 / (96 * 96);
    int r1 = r0 - d * (96 * 96);
    int hh = r1 / 96;
    int ww = r1 - hh * 96;
    int bp = b * 144 + (hh >> 3) * 12 + (ww >> 3);
    int l  = d * 64 + (hh & 7) * 8 + (ww & 7);
    unsigned short* hp = h + ((size_t)bp * 512 + l) * 192;
    hp[lane]       = f2bf(d0 * rs * g[lane]       + bsh[lane]);
    hp[lane + 64]  = f2bf(d1 * rs * g[lane + 64]  + bsh[lane + 64]);
    hp[lane + 128] = f2bf(d2 * rs * g[lane + 128] + bsh[lane + 128]);
}

// ---------------------------------------------------------------------------
// K5: LayerNorm(norm4), natural layout -> xn4 bf16
// ---------------------------------------------------------------------------
__global__ __launch_bounds__(256) void k_ln4(const float* __restrict__ yv,
                                             const float* __restrict__ g,
                                             const float* __restrict__ bsh,
                                             unsigned short* __restrict__ xn) {
    int w = threadIdx.x >> 6, lane = threadIdx.x & 63;
    size_t token = (size_t)blockIdx.x * 4 + w;
    const float* xp = yv + token * 192;
    float v0 = xp[lane], v1 = xp[lane + 64], v2 = xp[lane + 128];
    float s = v0 + v1 + v2;
#pragma unroll
    for (int off = 32; off; off >>= 1) s += __shfl_xor(s, off);
    float mean = s * (1.f / 192.f);
    float d0 = v0 - mean, d1 = v1 - mean, d2 = v2 - mean;
    float q = d0 * d0 + d1 * d1 + d2 * d2;
#pragma unroll
    for (int off = 32; off; off >>= 1) q += __shfl_xor(q, off);
    float rs = rsqrtf(q * (1.f / 192.f) + 1e-5f);
    unsigned short* op = xn + token * 192;
    op[lane]       = f2bf(d0 * rs * g[lane]       + bsh[lane]);
    op[lane + 64]  = f2bf(d1 * rs * g[lane + 64]  + bsh[lane + 64]);
    op[lane + 128] = f2bf(d2 * rs * g[lane + 128] + bsh[lane + 128]);
}

// ---------------------------------------------------------------------------
// K2: 128x128-tile GEMM via global_load_lds(16B) with XOR-swizzled chunks.
// LDS linear [128][64]; phys chunk c of row r holds logical chunk c^(r&7)
// (swizzle applied at the per-lane GLOBAL source; reads apply the same XOR)
// => ds_read_b128 is 2-way-aliased only (free). XCD-swizzled block order.
// EPI 0: qkv -> qk (q scaled) + vt (v transposed, packed 8B)
// EPI 1: out_proj -> window-reverse + x residual -> y fp32 (=d_out)
// EPI 2: fc1 + exact gelu -> hidden bf16
// EPI 3: fc2 + y residual -> out fp32 (in-place on d_out)
// ---------------------------------------------------------------------------
template <int EPI, int K>
__global__ __launch_bounds__(256) void k_gemm128(const unsigned short* __restrict__ A,
                                                 const unsigned short* __restrict__ Bw,
                                                 const float* __restrict__ bias,
                                                 unsigned short* __restrict__ outb,
                                                 unsigned short* __restrict__ vt,
                                                 float* __restrict__ outf,
                                                 const float* __restrict__ res) {
    __shared__ unsigned short As[128 * 64];
    __shared__ unsigned short Bs[128 * 64];
    const int tid = threadIdx.x;
    // XCD-aware swizzle of the flat block id (nwg = gridDim.x*1152, %8==0)
    const int nwg = gridDim.x * gridDim.y;
    const int flat = blockIdx.y * gridDim.x + blockIdx.x;
    const int swz = (flat & 7) * (nwg >> 3) + (flat >> 3);
    const int bx = swz % gridDim.x, by = swz / gridDim.x;
    const int row0 = by * 128, col0 = bx * 128;
    const int wv = tid >> 6, lane = tid & 63, lr = lane & 15, lg = lane >> 4;
    const int wr = wv >> 1, wc = wv & 1;
    const int sr = lane >> 3, sc = lane & 7;     // staging: 8 rows x 8 chunks / inst
    f32x4 acc[4][4] = {};

    for (int k0 = 0; k0 < K; k0 += 64) {
#pragma unroll
        for (int i = 0; i < 4; i++) {
            int g = wv * 4 + i;                  // 1KB group = rows [g*8, g*8+8)
            int r = g * 8 + sr;
            int j = sc ^ (r & 7);                // swizzled source chunk
            gl_lds16(A + (size_t)(row0 + r) * K + k0 + j * 8, &As[g * 512]);
        }
#pragma unroll
        for (int i = 0; i < 4; i++) {
            int g = wv * 4 + i;
            int r = g * 8 + sr;
            int j = sc ^ (r & 7);
            gl_lds16(Bw + (size_t)(col0 + r) * K + k0 + j * 8, &Bs[g * 512]);
        }
        __syncthreads();                         // vmcnt(0) drained by compiler
#pragma unroll
        for (int kk = 0; kk < 64; kk += 32) {
            bf16x8 af[4], bf[4];
#pragma unroll
            for (int m = 0; m < 4; m++) {
                int r = wr * 64 + m * 16 + lr;
                int j = ((kk >> 3) + lg) ^ (r & 7);
                af[m] = __builtin_bit_cast(bf16x8,
                    *reinterpret_cast<const u32x4*>(&As[r * 64 + j * 8]));
            }
#pragma unroll
            for (int n = 0; n < 4; n++) {
                int r = wc * 64 + n * 16 + lr;
                int j = ((kk >> 3) + lg) ^ (r & 7);
                bf[n] = __builtin_bit_cast(bf16x8,
                    *reinterpret_cast<const u32x4*>(&Bs[r * 64 + j * 8]));
            }
#pragma unroll
            for (int m = 0; m < 4; m++)
#pragma unroll
                for (int n = 0; n < 4; n++)
                    acc[m][n] = __builtin_amdgcn_mfma_f32_16x16x32_bf16(af[m], bf[n], acc[m][n], 0, 0, 0);
        }
        __syncthreads();
    }

#pragma unroll
    for (int m = 0; m < 4; m++) {
#pragma unroll
        for (int n = 0; n < 4; n++) {
            int col  = col0 + wc * 64 + n * 16 + lr;
            int rowb = row0 + wr * 64 + m * 16 + lg * 4;
            if constexpr (EPI == 0) {
                if (col < 384) {
                    float b = bias[col];
                    float sc2 = (col < 192) ? 0.1020620726159658f : 1.f;  // 1/sqrt(96) on q
#pragma unroll
                    for (int rr = 0; rr < 4; rr++)
                        outb[(size_t)(rowb + rr) * 384 + col] = f2bf((acc[m][n][rr] + b) * sc2);
                } else if (col < 576) {
                    float b = bias[col];
                    int head = (col >= 480) ? 1 : 0;
                    int d = col - 384 - head * 96;
                    int bp = rowb >> 9, tok = rowb & 511;
                    u16x4 pk = { f2bf(acc[m][n][0] + b), f2bf(acc[m][n][1] + b),
                                 f2bf(acc[m][n][2] + b), f2bf(acc[m][n][3] + b) };
                    *reinterpret_cast<u16x4*>(vt + ((size_t)(bp * 2 + head) * 96 + d) * 512 + tok) = pk;
                }
            } else if constexpr (EPI == 1) {
                if (col < 192) {
                    float b = bias[col];
#pragma unroll
                    for (int rr = 0; rr < 4; rr++) {
                        int nrow = rowb + rr;
                        int bp = nrow >> 9, l = nrow & 511;
                        int bb = bp / 144, p = bp - bb * 144;
                        int hn = p / 12, wn = p - hn * 12;
                        int dn = l >> 6, t_ = l & 63;
                        size_t tok = ((size_t)((bb * 8 + dn) * 96 + hn * 8 + (t_ >> 3)) * 96 + wn * 8 + (t_ & 7));
                        size_t idx = tok * 192 + col;
                        outf[idx] = res[idx] + acc[m][n][rr] + b;
                    }
                }
            } else if constexpr (EPI == 2) {
                float b = bias[col];
#pragma unroll
                for (int rr = 0; rr < 4; rr++) {
                    float v = acc[m][n][rr] + b;
                    float gz = 0.5f * v * (1.f + erff(v * 0.70710678118654752f));
                    outb[(size_t)(rowb + rr) * 768 + col] = f2bf(gz);
                }
            } else {
                if (col < 192) {
                    float b = bias[col];
#pragma unroll
                    for (int rr = 0; rr < 4; rr++) {
                        size_t idx = (size_t)(rowb + rr) * 192 + col;
                        outf[idx] = res[idx] + acc[m][n][rr] + b;
                    }
                }
            }
        }
    }
}

// ---------------------------------------------------------------------------
// K3: block-causal attention, dnq-paired 8-wave WG.
// One WG (512 thr) per (bp, head, pair p): waves 0-3 own tile A (dnq=2p),
// waves 4-7 own tile B (dnq=2p+1); wave owns 16 q-rows. Loop dnk=0..2p+1:
// K/V staged ONCE per dnk, shared by both tiles; async-split staging (issue
// next tile's global loads into regs during compute, commit after barrier).
// Swapped QK^T (mfma(K,Q)) keeps softmax in-register as in round 3.
// ---------------------------------------------------------------------------
__global__ __launch_bounds__(512) void k_attn(const unsigned short* __restrict__ qk,
                                              const unsigned short* __restrict__ vt,
                                              unsigned short* __restrict__ aout) {
    __shared__ unsigned short Ks[64][104];
    __shared__ unsigned short Vs[96][72];
    __shared__ unsigned short Ps[8][16][72];

    // XCD swizzle: all 8 (head,pair) WGs of one bp share K/V in one XCD's L2
    int bid = (blockIdx.x & 7) * 288 + (blockIdx.x >> 3);   // 2304 % 8 == 0
    int bp = bid >> 3, rest = bid & 7, head = rest >> 2, pr = rest & 3;
    int tid = threadIdx.x, wv = tid >> 6, lane = tid & 63;
    int lr = lane & 15, lg = lane >> 4;
    int wq = wv & 3, wt = wv >> 2;           // wt: 0 = dnq=2p, 1 = dnq=2p+1
    int nk = 2 * pr + 2;

    size_t qrow0 = (size_t)bp * 512 + (size_t)(2 * pr + wt) * 64;
    const unsigned short* vbase = vt + (size_t)(bp * 2 + head) * 96 * 512;
    size_t krowb = (size_t)bp * 512;

    // Q as B-fragments (col = q-row = lr)
    bf16x8 qf[3];
    {
        const unsigned short* qp = qk + (qrow0 + wq * 16 + lr) * 384 + head * 96 + lg * 8;
#pragma unroll
        for (int ks = 0; ks < 3; ks++)
            qf[ks] = __builtin_bit_cast(bf16x8, *reinterpret_cast<const u32x4*>(qp + ks * 32));
    }

    f32x4 o[6] = {};
    float m_ = -1e30f, lsum = 0.f;

    // staging: 768 K-chunks + 768 V-chunks of 16B over 512 threads = 3 each
    u32x4 sreg[3];
    auto issue = [&](int dnk) {
#pragma unroll
        for (int i = 0; i < 3; i++) {
            int c = tid + i * 512;
            if (c < 768) {
                int r = c / 12, cc = c - r * 12;
                sreg[i] = *reinterpret_cast<const u32x4*>(
                    qk + (krowb + dnk * 64 + r) * 384 + 192 + head * 96 + cc * 8);
            } else {
                int c2 = c - 768; int d = c2 >> 3, tb = c2 & 7;
                sreg[i] = *reinterpret_cast<const u32x4*>(
                    vbase + (size_t)d * 512 + dnk * 64 + tb * 8);
            }
        }
    };
    auto commit = [&]() {
#pragma unroll
        for (int i = 0; i < 3; i++) {
            int c = tid + i * 512;
            if (c < 768) {
                int r = c / 12, cc = c - r * 12;
                *reinterpret_cast<u32x4*>(&Ks[r][cc * 8]) = sreg[i];
            } else {
                int c2 = c - 768; int d = c2 >> 3, tb = c2 & 7;
                *reinterpret_cast<u32x4*>(&Vs[d][tb * 8]) = sreg[i];
            }
        }
    };

    issue(0);
    for (int dnk = 0; dnk < nk; ++dnk) {
        commit();
        __syncthreads();                      // K/V tile visible
        if (dnk + 1 < nk) issue(dnk + 1);     // prefetch next tile under compute
        if (wt == 1 || dnk < nk - 1) {        // tile A skips only the last stage
            // S^T = K Q^T : lane holds S[qrow=lr][kcol = ct*16 + lg*4 + rr]
            f32x4 st[4] = {};
#pragma unroll
            for (int ks = 0; ks < 3; ks++) {
#pragma unroll
                for (int ct = 0; ct < 4; ct++) {
                    bf16x8 kf = __builtin_bit_cast(bf16x8,
                        *reinterpret_cast<const u32x4*>(&Ks[ct * 16 + lr][ks * 32 + lg * 8]));
                    st[ct] = __builtin_amdgcn_mfma_f32_16x16x32_bf16(kf, qf[ks], st[ct], 0, 0, 0);
                }
            }
            // online softmax for q-row lr (lanes {lr, lr+16, lr+32, lr+48})
            float mx = st[0][0];
#pragma unroll
            for (int ct = 0; ct < 4; ct++)
#pragma unroll
                for (int rr = 0; rr < 4; rr++) mx = fmaxf(mx, st[ct][rr]);
            mx = fmaxf(mx, __shfl_xor(mx, 16));
            mx = fmaxf(mx, __shfl_xor(mx, 32));
            float mnew = fmaxf(m_, mx);
            float corr = __expf(m_ - mnew);
            m_ = mnew;
            float ps = 0.f;
#pragma unroll
            for (int ct = 0; ct < 4; ct++) {
                u16x4 pk;
#pragma unroll
                for (int rr = 0; rr < 4; rr++) {
                    float pv = __expf(st[ct][rr] - mnew);
                    ps += pv;
                    pk[rr] = f2bf(pv);
                }
                *reinterpret_cast<u16x4*>(&Ps[wv][lr][ct * 16 + lg * 4]) = pk;
            }
            ps += __shfl_xor(ps, 16);
            ps += __shfl_xor(ps, 32);
            lsum = lsum * corr + ps;
            // rescale O (broadcast corr of row lg*4+rr)
#pragma unroll
            for (int rr = 0; rr < 4; rr++) {
                float cr = __shfl(corr, (lane & 48) | (lg * 4 + rr));
#pragma unroll
                for (int nf = 0; nf < 6; nf++) o[nf][rr] *= cr;
            }
            // PV: O += P @ V
#pragma unroll
            for (int kk = 0; kk < 2; kk++) {
                bf16x8 pf = __builtin_bit_cast(bf16x8,
                    *reinterpret_cast<const u32x4*>(&Ps[wv][lr][kk * 32 + lg * 8]));
#pragma unroll
                for (int nf = 0; nf < 6; nf++) {
                    bf16x8 vf = __builtin_bit_cast(bf16x8,
                        *reinterpret_cast<const u32x4*>(&Vs[nf * 16 + lr][kk * 32 + lg * 8]));
                    o[nf] = __builtin_amdgcn_mfma_f32_16x16x32_bf16(pf, vf, o[nf], 0, 0, 0);
                }
            }
        }
        __syncthreads();                      // all reads done before next commit
    }

    // epilogue: divide by lsum (broadcast per row), store bf16
#pragma unroll
    for (int rr = 0; rr < 4; rr++) {
        float li = __shfl(lsum, (lane & 48) | (lg * 4 + rr));
        float inv = 1.f / li;
        size_t row = qrow0 + wq * 16 + lg * 4 + rr;
#pragma unroll
        for (int nf = 0; nf < 6; nf++)
            aout[row * 192 + head * 96 + nf * 16 + lr] = f2bf(o[nf][rr] * inv);
    }
}

// ---------------------------------------------------------------------------
// Launcher. y lives in d_out (fully rewritten each call => replay safe).
// ws arena (~284.2 MB):
//   [0, 113.2M)        qk bf16 [147456][384]   } hidden [147456][768]
//   [113.2M, 169.9M)   vt bf16 [576][96][512]  }   aliases [0, 226.5M)
//   [169.9M, 226.5M)   h  bf16 [147456][192]   }   at fc1/fc2 time
//   [226.5M, 283.1M)   attn bf16 ; xn4 aliases it after out_proj
//   [283.1M, 284.2M)   bf16 padded weights
// ---------------------------------------------------------------------------
extern "C" void kernel_launch(void* const* d_in, const int* in_sizes, int n_in,
                              void* d_out, int out_size, void* d_ws, size_t ws_size,
                              hipStream_t stream) {
    const float* x    = (const float*)d_in[0];
    const float* n3g  = (const float*)d_in[1];
    const float* n3b  = (const float*)d_in[2];
    const float* wqkv = (const float*)d_in[3];
    const float* bqkv = (const float*)d_in[4];
    const float* wout = (const float*)d_in[5];
    const float* bout = (const float*)d_in[6];
    const float* n4g  = (const float*)d_in[7];
    const float* n4b  = (const float*)d_in[8];
    const float* wfc1 = (const float*)d_in[9];
    const float* bfc1 = (const float*)d_in[10];
    const float* wfc2 = (const float*)d_in[11];
    const float* bfc2 = (const float*)d_in[12];
    float* out = (float*)d_out;

    char* ws = (char*)d_ws;
    unsigned short* qk     = (unsigned short*)(ws + 0);
    unsigned short* vt     = (unsigned short*)(ws + 113246208);
    unsigned short* h      = (unsigned short*)(ws + 169869312);
    unsigned short* attn   = (unsigned short*)(ws + 226492416);
    unsigned short* xn4    = (unsigned short*)(ws + 226492416);   // alias attn
    unsigned short* hidden = (unsigned short*)(ws + 0);           // alias qk+vt+h
    unsigned short* wq_bf  = (unsigned short*)(ws + 283115520);
    unsigned short* wo_bf  = (unsigned short*)(ws + 283361280);
    unsigned short* w1_bf  = (unsigned short*)(ws + 283459584);
    unsigned short* w2_bf  = (unsigned short*)(ws + 283754496);
    float* y = out;   // y = x + attn-out lives in d_out

    k_wconv<<<2016, 256, 0, stream>>>(wqkv, wout, wfc1, wfc2, wq_bf, wo_bf, w1_bf, w2_bf);
    k_ln3<<<36864, 256, 0, stream>>>(x, n3g, n3b, h);
    k_gemm128<0, 192><<<dim3(5, 1152), 256, 0, stream>>>(h, wq_bf, bqkv, qk, vt, nullptr, nullptr);
    k_attn<<<2304, 512, 0, stream>>>(qk, vt, attn);
    k_gemm128<1, 192><<<dim3(2, 1152), 256, 0, stream>>>(attn, wo_bf, bout, nullptr, nullptr, y, x);
    k_ln4<<<36864, 256, 0, stream>>>(y, n4g, n4b, xn4);
    k_gemm128<2, 192><<<dim3(6, 1152), 256, 0, stream>>>(xn4, w1_bf, bfc1, hidden, nullptr, nullptr, nullptr);
    k_gemm128<3, 768><<<dim3(2, 1152), 256, 0, stream>>>(hidden, w2_bf, bfc2, nullptr, nullptr, out, y);
}